// Round 4
// baseline (6631.782 us; speedup 1.0000x reference)
//
#include <hip/hip_runtime.h>
#include <hip/hip_bf16.h>
#include <cstdint>
#include <cstddef>

// Problem constants
// L=256, B=16, I=2048, H=2048, S=R=T=32
#define L_DIM 256
#define B_DIM 16
#define I_DIM 2048
#define H_DIM 2048
#define G4    8192            // 4*H
#define MROWS 4096            // L*B
#define TCHUNK 32             // LSTM timesteps per Gin chunk

typedef __hip_bfloat16 bf16;
typedef __bf16 bf16x8_t __attribute__((ext_vector_type(8)));
typedef float f32x4_t   __attribute__((ext_vector_type(4)));

__device__ __forceinline__ bf16 f2b(float f) { return __float2bfloat16(f); }

__device__ __forceinline__ void gl_lds16(const void* g, void* l) {
  __builtin_amdgcn_global_load_lds(
      (const __attribute__((address_space(1))) unsigned int*)g,
      (__attribute__((address_space(3))) unsigned int*)l, 16, 0, 0);
}

__device__ __forceinline__ float sigmoidf_(float x) { return 1.f / (1.f + expf(-x)); }

// ---------------------------------------------------------------------------
// K0: prep — hi/lo split casts, bias combine, padded Ww, state init
// ---------------------------------------------------------------------------
__global__ void prep_kernel(const float* __restrict__ Wih, const float* __restrict__ Whh,
                            const float* __restrict__ inp, const float* __restrict__ bih,
                            const float* __restrict__ bhh, const float* __restrict__ Www,
                            const float* __restrict__ Wwb, const float* __restrict__ Wrw,
                            const float* __restrict__ h0,  const float* __restrict__ c0,
                            bf16* __restrict__ Wih_hi, bf16* __restrict__ Wih_lo,
                            bf16* __restrict__ Whh_hi, bf16* __restrict__ Whh_lo,
                            bf16* __restrict__ inp_hi, bf16* __restrict__ inp_lo,
                            float* __restrict__ cb,
                            bf16* __restrict__ Wq_hi, bf16* __restrict__ Wq_lo,
                            bf16* __restrict__ Wr_hi, bf16* __restrict__ Wr_lo,
                            float* __restrict__ wbpad,
                            bf16* __restrict__ h_hi0, bf16* __restrict__ h_lo0,
                            float* __restrict__ cbuf)
{
  size_t idx0 = (size_t)blockIdx.x * blockDim.x + threadIdx.x;
  size_t stride = (size_t)gridDim.x * blockDim.x;
  for (size_t i = idx0; i < 16777216ull; i += stride) {
    float a = Wih[i];
    bf16 ah = f2b(a);
    Wih_hi[i] = ah;
    Wih_lo[i] = f2b(a - (float)ah);
    float b = Whh[i];
    bf16 bh = f2b(b);
    Whh_hi[i] = bh;
    Whh_lo[i] = f2b(b - (float)bh);
  }
  for (size_t i = idx0; i < 8388608ull; i += stride) {
    float a = inp[i];
    bf16 ah = f2b(a);
    inp_hi[i] = ah;
    inp_lo[i] = f2b(a - (float)ah);
  }
  for (size_t i = idx0; i < 8192ull; i += stride) cb[i] = bih[i] + bhh[i];
  for (size_t i = idx0; i < 262144ull; i += stride) {
    size_t r = i >> 11;                       // row index (2048 cols)
    float q = (r < 97) ? Www[i] : 0.f;
    bf16 qh = f2b(q);
    Wq_hi[i] = qh;
    Wq_lo[i] = f2b(q - (float)qh);
    float rr = Wrw[i];
    bf16 rh = f2b(rr);
    Wr_hi[i] = rh;
    Wr_lo[i] = f2b(rr - (float)rh);
  }
  for (size_t i = idx0; i < 128ull; i += stride) wbpad[i] = (i < 97) ? Wwb[i] : 0.f;
  for (size_t i = idx0; i < 32768ull; i += stride) {
    float h = h0[i];
    bf16 hh = f2b(h);
    h_hi0[i] = hh;
    h_lo0[i] = f2b(h - (float)hh);
    cbuf[i]  = c0[i];
  }
}

// ---------------------------------------------------------------------------
// K1: split-bf16 (hi+lo) NT GEMM — effective ~fp32 accuracy via 3 products:
//   C = A_hi*B_hi^T + A_hi*B_lo^T + A_lo*B_hi^T (+bias)
// 128x128 tile, BK=32, 256 threads (4 waves, 2x2 of 64x64), global_load_lds.
// MODE 1: C = acc + bias ; MODE 2: C = tanh(acc + bias)
// ---------------------------------------------------------------------------
template <int MODE>
__global__ __launch_bounds__(256) void gemm_nt3(const bf16* __restrict__ A_hi,
                                                const bf16* __restrict__ A_lo,
                                                const bf16* __restrict__ B_hi,
                                                const bf16* __restrict__ B_lo,
                                                const float* __restrict__ bias,
                                                float* __restrict__ C,
                                                int M, int N, int K)
{
  __shared__ __align__(16) bf16 As[2][128 * 32];
  __shared__ __align__(16) bf16 Bs[2][128 * 32];
  const int tid  = threadIdx.x;
  const int lane = tid & 63;
  const int w    = tid >> 6;
  const int wm   = w >> 1, wn = w & 1;
  const int m0   = blockIdx.x * 128, n0 = blockIdx.y * 128;

  f32x4_t acc[4][4];
#pragma unroll
  for (int m = 0; m < 4; ++m)
#pragma unroll
    for (int n = 0; n < 4; ++n) acc[m][n] = (f32x4_t){0.f, 0.f, 0.f, 0.f};

  for (int k0 = 0; k0 < K; k0 += 32) {
#pragma unroll
    for (int r = 0; r < 2; ++r) {
      const int base = w * 2048 + r * 1024;
      const int off  = base + lane * 16;
      const int e    = off >> 1;
      const int row  = e >> 5;
      const int col  = e & 31;
      const size_t gA = (size_t)(m0 + row) * K + (k0 + col);
      const size_t gB = (size_t)(n0 + row) * K + (k0 + col);
      gl_lds16(A_hi + gA, (char*)As[0] + base);
      gl_lds16(A_lo + gA, (char*)As[1] + base);
      gl_lds16(B_hi + gB, (char*)Bs[0] + base);
      gl_lds16(B_lo + gB, (char*)Bs[1] + base);
    }
    __syncthreads();

    bf16x8_t afh[4], afl[4], bfh[4], bfl[4];
    const int kb = (lane >> 4) * 16;
#pragma unroll
    for (int m = 0; m < 4; ++m) {
      const int ro = (wm * 64 + m * 16 + (lane & 15)) * 64 + kb;
      afh[m] = *reinterpret_cast<const bf16x8_t*>((const char*)As[0] + ro);
      afl[m] = *reinterpret_cast<const bf16x8_t*>((const char*)As[1] + ro);
    }
#pragma unroll
    for (int n = 0; n < 4; ++n) {
      const int ro = (wn * 64 + n * 16 + (lane & 15)) * 64 + kb;
      bfh[n] = *reinterpret_cast<const bf16x8_t*>((const char*)Bs[0] + ro);
      bfl[n] = *reinterpret_cast<const bf16x8_t*>((const char*)Bs[1] + ro);
    }
#pragma unroll
    for (int m = 0; m < 4; ++m)
#pragma unroll
      for (int n = 0; n < 4; ++n) {
        acc[m][n] = __builtin_amdgcn_mfma_f32_16x16x32_bf16(afh[m], bfh[n], acc[m][n], 0, 0, 0);
        acc[m][n] = __builtin_amdgcn_mfma_f32_16x16x32_bf16(afh[m], bfl[n], acc[m][n], 0, 0, 0);
        acc[m][n] = __builtin_amdgcn_mfma_f32_16x16x32_bf16(afl[m], bfh[n], acc[m][n], 0, 0, 0);
      }
    __syncthreads();
  }

#pragma unroll
  for (int m = 0; m < 4; ++m) {
#pragma unroll
    for (int n = 0; n < 4; ++n) {
      const int col = n0 + wn * 64 + n * 16 + (lane & 15);
      const float bv = bias[col];
#pragma unroll
      for (int r = 0; r < 4; ++r) {
        const int row = m0 + wm * 64 + m * 16 + (lane >> 4) * 4 + r;
        float v = acc[m][n][r] + bv;
        if (MODE == 2) v = tanhf(v);
        C[(size_t)row * N + col] = v;
      }
    }
  }
}

// ---------------------------------------------------------------------------
// K2: one LSTM step (split-bf16 h and W_hh; ~fp32-accurate h@W_hh^T).
// 256 WGs x 256 thr. WG owns 8 hidden units j in [8*wg, 8*wg+8) across all
// 4 gates (32 W_hh rows). K split across 4 waves.
// ---------------------------------------------------------------------------
__global__ __launch_bounds__(256) void lstm_step(const bf16* __restrict__ Whh_hi,
                                                 const bf16* __restrict__ Whh_lo,
                                                 const float* __restrict__ Gin_t,
                                                 const bf16* __restrict__ h_in_hi,
                                                 const bf16* __restrict__ h_in_lo,
                                                 bf16* __restrict__ h_out_hi,
                                                 bf16* __restrict__ h_out_lo,
                                                 float* __restrict__ c,
                                                 float* __restrict__ Xf,
                                                 bf16* __restrict__ Xb_hi,
                                                 bf16* __restrict__ Xb_lo,
                                                 int t)
{
  __shared__ float part[4][2][16][16];   // [wave][tile][batch][n]
  const int tid  = threadIdx.x;
  const int lane = tid & 63;
  const int w    = tid >> 6;
  const int j0   = blockIdx.x * 8;

  f32x4_t acc0 = {0.f, 0.f, 0.f, 0.f}, acc1 = {0.f, 0.f, 0.f, 0.f};

  const int bA  = lane & 15;           // batch row (A operand)
  const int kA  = (lane >> 4) * 8;     // k sub-offset
  const int nl0 = lane & 15;           // n within 16x16 tile
  const int jj_ = nl0 & 7, gt_ = nl0 >> 3;
  const size_t rowB0 = (size_t)((0 + gt_) * H_DIM + j0 + jj_) * 2048;  // gates i/f
  const size_t rowB1 = (size_t)((2 + gt_) * H_DIM + j0 + jj_) * 2048;  // gates g/o
  const size_t rowA  = (size_t)bA * 2048;

#pragma unroll 4
  for (int it = 0; it < 16; ++it) {
    const int k = w * 512 + it * 32 + kA;
    bf16x8_t ah  = *reinterpret_cast<const bf16x8_t*>(h_in_hi + rowA + k);
    bf16x8_t al  = *reinterpret_cast<const bf16x8_t*>(h_in_lo + rowA + k);
    bf16x8_t b0h = *reinterpret_cast<const bf16x8_t*>(Whh_hi + rowB0 + k);
    bf16x8_t b0l = *reinterpret_cast<const bf16x8_t*>(Whh_lo + rowB0 + k);
    bf16x8_t b1h = *reinterpret_cast<const bf16x8_t*>(Whh_hi + rowB1 + k);
    bf16x8_t b1l = *reinterpret_cast<const bf16x8_t*>(Whh_lo + rowB1 + k);
    acc0 = __builtin_amdgcn_mfma_f32_16x16x32_bf16(ah, b0h, acc0, 0, 0, 0);
    acc0 = __builtin_amdgcn_mfma_f32_16x16x32_bf16(ah, b0l, acc0, 0, 0, 0);
    acc0 = __builtin_amdgcn_mfma_f32_16x16x32_bf16(al, b0h, acc0, 0, 0, 0);
    acc1 = __builtin_amdgcn_mfma_f32_16x16x32_bf16(ah, b1h, acc1, 0, 0, 0);
    acc1 = __builtin_amdgcn_mfma_f32_16x16x32_bf16(ah, b1l, acc1, 0, 0, 0);
    acc1 = __builtin_amdgcn_mfma_f32_16x16x32_bf16(al, b1h, acc1, 0, 0, 0);
  }
#pragma unroll
  for (int r = 0; r < 4; ++r) {
    part[w][0][(lane >> 4) * 4 + r][lane & 15] = acc0[r];
    part[w][1][(lane >> 4) * 4 + r][lane & 15] = acc1[r];
  }
  __syncthreads();

  if (tid < 128) {
    const int bb = tid & 15, jj = tid >> 4;
    float g[4];
#pragma unroll
    for (int gate = 0; gate < 4; ++gate) {
      const int n = gate * 8 + jj;
      const int tile = n >> 4, nn = n & 15;
      float s = part[0][tile][bb][nn] + part[1][tile][bb][nn] +
                part[2][tile][bb][nn] + part[3][tile][bb][nn];
      g[gate] = s + Gin_t[(size_t)bb * G4 + gate * H_DIM + j0 + jj];
    }
    const int cidx = bb * H_DIM + j0 + jj;
    const float ci = c[cidx];
    const float i_ = sigmoidf_(g[0]);
    const float f_ = sigmoidf_(g[1]);
    const float gg = tanhf(g[2]);
    const float o_ = sigmoidf_(g[3]);
    const float cn = f_ * ci + i_ * gg;
    const float h  = o_ * tanhf(cn);
    c[cidx] = cn;
    const bf16 hh = f2b(h);
    const bf16 hl = f2b(h - (float)hh);
    h_out_hi[cidx] = hh;
    h_out_lo[cidx] = hl;
    const size_t xi = (size_t)(t * 16 + bb) * H_DIM + j0 + jj;
    Xf[xi] = h;
    Xb_hi[xi] = hh;
    Xb_lo[xi] = hl;
  }
}

// ---------------------------------------------------------------------------
// K3: FWM scan. 16 WGs (one per batch) x 1024 thr (16 waves).
// Fm register-resident: wave wv owns t in {2wv, 2wv+1}; lane owns k in
// [16*lane, 16*lane+16).  F[i][j] = Fm[16*lane+i][2*wv+j].
// ---------------------------------------------------------------------------
__global__ __launch_bounds__(1024) void fwm_scan(const float* __restrict__ Wall,   // (4096,128)
                                                 const float* __restrict__ RVall,  // (4096,128)
                                                 const float* __restrict__ F0,     // (16,1024,32)
                                                 float* __restrict__ QS)           // (4096,32)
{
  const int b    = blockIdx.x;
  const int tid  = threadIdx.x;
  const int lane = tid & 63;
  const int wv   = tid >> 6;

  __shared__ float s_s[32], s_r[32], s_tv[32], s_bb;
  __shared__ float s_rv[128];
  __shared__ float s_v[32], s_u[32], s_q[32];
  __shared__ float s_red[16];
  __shared__ float s_inv;

  float F[16][2];
#pragma unroll
  for (int i = 0; i < 16; ++i)
#pragma unroll
    for (int j = 0; j < 2; ++j)
      F[i][j] = F0[((size_t)b * 1024 + (16 * lane + i)) * 32 + 2 * wv + j];

  const int si    = lane >> 1;        // s / q index for this lane's k-range
  const int rbase = 16 * (lane & 1);  // r / rj base index

  for (int t = 0; t < 256; ++t) {
    const float* wrow  = Wall  + (size_t)(t * 16 + b) * 128;
    const float* rvrow = RVall + (size_t)(t * 16 + b) * 128;
    __syncthreads();   // protect shared staging vs previous-step readers
    if (tid < 32)            s_s[tid]        = tanhf(wrow[tid]);
    else if (tid < 64)       s_r[tid - 32]   = tanhf(wrow[tid]);
    else if (tid < 96)       s_tv[tid - 64]  = tanhf(wrow[tid]);
    else if (tid == 96)      s_bb            = sigmoidf_(wrow[96] + 1.f);
    else if (tid >= 128 && tid < 256) s_rv[tid - 128] = rvrow[tid - 128];
    __syncthreads();

    const float sv = s_s[si];
    float sr[16];
#pragma unroll
    for (int i = 0; i < 16; ++i) sr[i] = sv * s_r[rbase + i];

    // v[t] = sum_k sr[k] * Fm[k][t]
    float p0 = 0.f, p1 = 0.f;
#pragma unroll
    for (int i = 0; i < 16; ++i) { p0 += sr[i] * F[i][0]; p1 += sr[i] * F[i][1]; }
#pragma unroll
    for (int m = 1; m < 64; m <<= 1) { p0 += __shfl_xor(p0, m); p1 += __shfl_xor(p1, m); }
    if (lane == 0) { s_v[2 * wv] = p0; s_v[2 * wv + 1] = p1; }
    __syncthreads();

    if (tid < 32) s_u[tid] = s_bb * (s_tv[tid] - s_v[tid]);
    __syncthreads();

    // update (unscaled) + norm accumulation
    const float u0 = s_u[2 * wv], u1 = s_u[2 * wv + 1];
    float nn = 0.f;
#pragma unroll
    for (int i = 0; i < 16; ++i) {
      F[i][0] += sr[i] * u0;
      F[i][1] += sr[i] * u1;
      nn += F[i][0] * F[i][0] + F[i][1] * F[i][1];
    }
#pragma unroll
    for (int m = 1; m < 64; m <<= 1) nn += __shfl_xor(nn, m);
    if (lane == 0) s_red[wv] = nn;
    __syncthreads();
    if (tid == 0) {
      float tot = 0.f;
#pragma unroll
      for (int k = 0; k < 16; ++k) tot += s_red[k];
      const float n_ = sqrtf(tot);
      const float d  = fmaxf(n_ - 1.f, 0.f) + 1.f;
      s_inv = 1.f / d;
    }
    __syncthreads();
    const float inv = s_inv;
#pragma unroll
    for (int i = 0; i < 16; ++i) { F[i][0] *= inv; F[i][1] *= inv; }

    // q iterations
#pragma unroll 1
    for (int jit = 0; jit < 3; ++jit) {
      const float qv = (jit == 0) ? s_rv[si] : s_q[si];
      float c0 = 0.f, c1 = 0.f;
#pragma unroll
      for (int i = 0; i < 16; ++i) {
        const float cf = qv * s_rv[32 + 32 * jit + rbase + i];
        c0 += cf * F[i][0];
        c1 += cf * F[i][1];
      }
#pragma unroll
      for (int m = 1; m < 64; m <<= 1) { c0 += __shfl_xor(c0, m); c1 += __shfl_xor(c1, m); }
      if (lane == 0) { s_v[2 * wv] = c0; s_v[2 * wv + 1] = c1; }
      __syncthreads();
      if (wv == 0 && lane < 32) {
        const float x = s_v[lane];
        float mval = x;
#pragma unroll
        for (int m = 1; m < 32; m <<= 1) mval += __shfl_xor(mval, m);
        mval *= (1.f / 32.f);
        const float dl = x - mval;
        float var = dl * dl;
#pragma unroll
        for (int m = 1; m < 32; m <<= 1) var += __shfl_xor(var, m);
        var *= (1.f / 32.f);
        s_q[lane] = dl * rsqrtf(var + 1e-5f);
      }
      __syncthreads();
    }
    if (wv == 0 && lane < 32) QS[(size_t)(t * 16 + b) * 32 + lane] = s_q[lane];
  }
}

// ---------------------------------------------------------------------------
// K4: out = X + QS @ Wlin^T + blin
// ---------------------------------------------------------------------------
__global__ __launch_bounds__(256) void out_kernel(const float* __restrict__ Xf,
                                                  const float* __restrict__ QS,
                                                  const float* __restrict__ Wlin,  // (2048,32)
                                                  const float* __restrict__ blin,
                                                  float* __restrict__ out)
{
  __shared__ float qs[32];
  const int row = blockIdx.x;
  if (threadIdx.x < 32) qs[threadIdx.x] = QS[(size_t)row * 32 + threadIdx.x];
  __syncthreads();
  for (int h = threadIdx.x; h < H_DIM; h += 256) {
    float acc = Xf[(size_t)row * H_DIM + h] + blin[h];
    const float* wr = Wlin + (size_t)h * 32;
#pragma unroll
    for (int t2 = 0; t2 < 32; ++t2) acc += qs[t2] * wr[t2];
    out[(size_t)row * H_DIM + h] = acc;
  }
}

// ---------------------------------------------------------------------------
// Workspace (lifetime-aliased, peak ~221 MB):
//   Whh hi+lo 67MB | Wih hi+lo 67MB | inp hi+lo 34MB (Xb_hi/lo alias) |
//   Ginbuf 17MB (32-step chunk; Wall/RVall/QS alias after phase B) |
//   Xf 34MB | smalls ~2.6MB
// ---------------------------------------------------------------------------
extern "C" void kernel_launch(void* const* d_in, const int* in_sizes, int n_in,
                              void* d_out, int out_size, void* d_ws, size_t ws_size,
                              hipStream_t stream)
{
  (void)in_sizes; (void)n_in; (void)out_size; (void)ws_size;
  const float* inp  = (const float*)d_in[0];
  const float* h0   = (const float*)d_in[1];
  const float* c0   = (const float*)d_in[2];
  const float* F0   = (const float*)d_in[3];
  const float* Wih  = (const float*)d_in[4];
  const float* Whh  = (const float*)d_in[5];
  const float* bih  = (const float*)d_in[6];
  const float* bhh  = (const float*)d_in[7];
  const float* Www  = (const float*)d_in[8];
  const float* Wwb  = (const float*)d_in[9];
  const float* Wrw  = (const float*)d_in[10];
  const float* Wrb  = (const float*)d_in[11];
  const float* Wlin = (const float*)d_in[12];
  const float* blin = (const float*)d_in[13];
  float* out = (float*)d_out;

  char* p = (char*)d_ws;
  auto alloc = [&](size_t bytes) {
    char* r = p;
    p += (bytes + 255) & ~(size_t)255;
    return r;
  };
  bf16*  Whh_hi = (bf16*)alloc(16777216ull * 2);          // 33.5 MB
  bf16*  Whh_lo = (bf16*)alloc(16777216ull * 2);          // 33.5 MB
  bf16*  Wih_hi = (bf16*)alloc(16777216ull * 2);          // 33.5 MB
  bf16*  Wih_lo = (bf16*)alloc(16777216ull * 2);          // 33.5 MB
  bf16*  inp_hi = (bf16*)alloc(8388608ull * 2);           // 16.8 MB
  bf16*  inp_lo = (bf16*)alloc(8388608ull * 2);           // 16.8 MB
  float* Ginbuf = (float*)alloc((size_t)TCHUNK * 16 * G4 * 4); // 16.8 MB
  float* Xf     = (float*)alloc(8388608ull * 4);          // 33.5 MB
  bf16*  hbuf_hi = (bf16*)alloc(2 * 32768ull * 2);
  bf16*  hbuf_lo = (bf16*)alloc(2 * 32768ull * 2);
  float* cbuf   = (float*)alloc(32768ull * 4);
  float* cb     = (float*)alloc(8192ull * 4);
  bf16*  Wq_hi  = (bf16*)alloc(262144ull * 2);
  bf16*  Wq_lo  = (bf16*)alloc(262144ull * 2);
  bf16*  Wr_hi  = (bf16*)alloc(262144ull * 2);
  bf16*  Wr_lo  = (bf16*)alloc(262144ull * 2);
  float* wbpad  = (float*)alloc(128ull * 4);
  // aliases (strictly later lifetimes):
  bf16*  Xb_hi = inp_hi;                // Xb rows of chunk c written after inp rows of chunk c consumed
  bf16*  Xb_lo = inp_lo;
  float* Wall  = Ginbuf;                // 2 MB   (written after last lstm_step)
  float* RVall = Ginbuf + 524288;       // 2 MB
  float* QS    = Ginbuf + 1048576;      // 0.5 MB

  prep_kernel<<<2048, 256, 0, stream>>>(Wih, Whh, inp, bih, bhh, Www, Wwb, Wrw, h0, c0,
                                        Wih_hi, Wih_lo, Whh_hi, Whh_lo, inp_hi, inp_lo,
                                        cb, Wq_hi, Wq_lo, Wr_hi, Wr_lo, wbpad,
                                        hbuf_hi, hbuf_lo, cbuf);

  // Phases A+B interleaved: Gin chunk (32 steps, split-bf16), then LSTM steps.
  for (int chunk = 0; chunk < L_DIM / TCHUNK; ++chunk) {
    const size_t aoff = (size_t)chunk * TCHUNK * 16 * I_DIM;
    gemm_nt3<1><<<dim3(TCHUNK * 16 / 128, 64), 256, 0, stream>>>(
        inp_hi + aoff, inp_lo + aoff, Wih_hi, Wih_lo, cb, Ginbuf,
        TCHUNK * 16, G4, 2048);
    for (int tt = 0; tt < TCHUNK; ++tt) {
      const int t = chunk * TCHUNK + tt;
      lstm_step<<<256, 256, 0, stream>>>(Whh_hi, Whh_lo,
                                         Ginbuf + (size_t)tt * 16 * G4,
                                         hbuf_hi + (size_t)(t & 1) * 32768,
                                         hbuf_lo + (size_t)(t & 1) * 32768,
                                         hbuf_hi + (size_t)((t + 1) & 1) * 32768,
                                         hbuf_lo + (size_t)((t + 1) & 1) * 32768,
                                         cbuf, Xf, Xb_hi, Xb_lo, t);
    }
  }

  // Phase C: FWM projections for all timesteps (~fp32 via split-bf16)
  gemm_nt3<1><<<dim3(32, 1), 256, 0, stream>>>(Xb_hi, Xb_lo, Wq_hi, Wq_lo, wbpad,
                                               Wall, MROWS, 128, 2048);
  gemm_nt3<2><<<dim3(32, 1), 256, 0, stream>>>(Xb_hi, Xb_lo, Wr_hi, Wr_lo, Wrb,
                                               RVall, MROWS, 128, 2048);

  // Phase D: FWM scan (register-resident Fm, one WG per batch)
  fwm_scan<<<16, 1024, 0, stream>>>(Wall, RVall, F0, QS);

  // Phase E: out = X + QS @ Wlin^T + blin
  out_kernel<<<4096, 256, 0, stream>>>(Xf, QS, Wlin, blin, out);
}